// Round 2
// baseline (922.875 us; speedup 1.0000x reference)
//
#include <hip/hip_runtime.h>

// LTLIF(tau=2, decay_input=False, hard reset) -> Linear -> BN, x2 blocks, +skip.
// T=128, B=256, C=512. GEMMs: M=T*B=32768, K=N=512.
//
// Precision strategy (round 2): spike thresholding is a hard discontinuity, so
// h must match the reference to <1e-7 to avoid spike flips. GEMM is done in
// FULL FP64 via v_mfma_f64_16x16x4; BN stats in fp64; affine applied with a
// single f64->f32 rounding. LIF scan in f32: v*0.5+x is bit-identical to the
// reference's v-(v-0)*0.5+x (both roundings exact by Sterbenz). Spikes bf16
// (0/1 exact). Bias b absorbed by BN (skipped).

typedef __bf16 bf16;
typedef double f64x4 __attribute__((ext_vector_type(4)));

#define T_STEPS 128
#define BATCH   256
#define CH      512
#define BC      (BATCH * CH)        // 131072
#define MROWS   (T_STEPS * BATCH)   // 32768

// ---------------- async global->LDS (16B per lane, wave-uniform LDS base) ----
__device__ __forceinline__ void llds16(const void* g, void* l) {
  __builtin_amdgcn_global_load_lds(
      (const __attribute__((address_space(1))) void*)g,
      (__attribute__((address_space(3))) void*)l, 16, 0, 0);
}

// ---------------- W[d][c] f32 -> Wt[c][d] f64 (transposed for [k][n] LDS) ----
__global__ __launch_bounds__(256) void k_convw(const float* __restrict__ W,
                                               double* __restrict__ Wt) {
  int i = blockIdx.x * 256 + threadIdx.x;   // 262144
  int d = i >> 9, c = i & 511;
  Wt[(size_t)c * 512 + d] = (double)W[i];
}

// ---------------- LIF scan, block 1: x -> spikes (f32 scan, bit-exact) ------
__global__ __launch_bounds__(256) void k_lif1(const float* __restrict__ X,
                                              const float* __restrict__ wp,
                                              bf16* __restrict__ S) {
  int i = blockIdx.x * 256 + threadIdx.x;
  float inv_tau = 1.0f / (1.0f + expf(-wp[0]));  // sigmoid(0)=0.5 exact
  float om = 1.0f - inv_tau;
  float v = 0.0f;
  #pragma unroll 4
  for (int t = 0; t < T_STEPS; ++t) {
    float xt = X[(size_t)t * BC + i];
    v = v * om + xt;
    bool sp = (v >= 1.0f);
    S[(size_t)t * BC + i] = sp ? (bf16)1.0f : (bf16)0.0f;
    v = sp ? 0.0f : v;
  }
}

// ---------------- LIF scan, block 2: h = f32(f64(y)*a+b) -> spikes ----------
__global__ __launch_bounds__(256) void k_lif2(const float* __restrict__ Y,
                                              const double* __restrict__ sA,
                                              const double* __restrict__ sB,
                                              const float* __restrict__ wp,
                                              bf16* __restrict__ S) {
  int i = blockIdx.x * 256 + threadIdx.x;
  int c = i & (CH - 1);
  double a = sA[c], b = sB[c];
  float inv_tau = 1.0f / (1.0f + expf(-wp[0]));
  float om = 1.0f - inv_tau;
  float v = 0.0f;
  #pragma unroll 4
  for (int t = 0; t < T_STEPS; ++t) {
    float h = (float)((double)Y[(size_t)t * BC + i] * a + b);
    v = v * om + h;
    bool sp = (v >= 1.0f);
    S[(size_t)t * BC + i] = sp ? (bf16)1.0f : (bf16)0.0f;
    v = sp ? 0.0f : v;
  }
}

// ---------------- FP64 GEMM: Y[m][d] = sum_c S[m][c] * W[d][c] ---------------
// Tile 64(M) x 128(N), BK=32, 4 waves as 2x2; wave tile 32x64 = 2x4 frags.
// A staged bf16 [64][32] (row-major), B staged f64 [32][128] from Wt (k-major).
__global__ __launch_bounds__(256) void k_gemm(const bf16* __restrict__ S,
                                              const double* __restrict__ Wt,
                                              float* __restrict__ Y) {
  __shared__ bf16   Ab[64 * 32];     // 4 KB
  __shared__ double Bt[32 * 128];    // 32 KB

  const int tid  = threadIdx.x;
  const int wid  = tid >> 6;
  const int lane = tid & 63;
  const int bm = blockIdx.x >> 2;    // M/64 = 512
  const int bn = blockIdx.x & 3;     // N/128 = 4
  const int m0 = bm * 64;
  const int n0 = bn * 128;
  const int wm = wid >> 1, wn = wid & 1;

  f64x4 acc[2][4] = {};

  for (int kt = 0; kt < 512; kt += 32) {
    // stage A: 256 chunks of 16B; chunk=tid -> row=tid>>2, 8 bf16 at (tid&3)*8
    {
      int row = tid >> 2, c8 = tid & 3;
      llds16(S + (size_t)(m0 + row) * 512 + kt + c8 * 8,
             (char*)Ab + (size_t)wid * 1024);
    }
    // stage B: 2048 chunks of 16B; chunk cid -> k=cid>>6, 2 f64 at (cid&63)*2
    #pragma unroll
    for (int p = 0; p < 8; ++p) {
      int cid = p * 256 + tid;
      int k = cid >> 6, n2 = cid & 63;
      llds16(Wt + (size_t)(kt + k) * 512 + n0 + n2 * 2,
             (char*)Bt + (size_t)(p * 4 + wid) * 1024);
    }
    __syncthreads();

    #pragma unroll
    for (int s = 0; s < 8; ++s) {
      const int kl = (lane >> 4) + 4 * s;      // local k for this lane
      double a[2], b[4];
      #pragma unroll
      for (int m = 0; m < 2; ++m) {
        int row = wm * 32 + (lane & 15) + 16 * m;
        a[m] = (double)(float)Ab[row * 32 + kl];
      }
      #pragma unroll
      for (int n = 0; n < 4; ++n) {
        int col = wn * 64 + (lane & 15) + 16 * n;
        b[n] = Bt[kl * 128 + col];
      }
      #pragma unroll
      for (int m = 0; m < 2; ++m)
        #pragma unroll
        for (int n = 0; n < 4; ++n)
          acc[m][n] = __builtin_amdgcn_mfma_f64_16x16x4f64(a[m], b[n], acc[m][n], 0, 0, 0);
    }
    __syncthreads();
  }

  // C/D layout: col = lane&15, row = (lane>>4)*4 + q
  const int r0 = m0 + wm * 32 + (lane >> 4) * 4;
  const int c0 = n0 + wn * 64 + (lane & 15);
  #pragma unroll
  for (int m = 0; m < 2; ++m)
    #pragma unroll
    for (int n = 0; n < 4; ++n)
      #pragma unroll
      for (int q = 0; q < 4; ++q)
        Y[(size_t)(r0 + 16 * m + q) * 512 + (c0 + 16 * n)] = (float)acc[m][n][q];
}

// ---------------- BN stats stage 1: f64 partial sums per (block, channel) ---
__global__ __launch_bounds__(256) void k_stats1(const float* __restrict__ Y,
                                                double* __restrict__ sumP,
                                                double* __restrict__ sqP) {
  int b = blockIdx.x;       // 256 blocks x 128 rows
  int t = threadIdx.x;      // channels 2t, 2t+1
  const float2* base = (const float2*)(Y + (size_t)b * 128 * CH) + t;
  double s0 = 0, q0 = 0, s1 = 0, q1 = 0;
  #pragma unroll 4
  for (int r = 0; r < 128; ++r) {
    float2 v = base[(size_t)r * 256];
    double x = v.x, y = v.y;
    s0 += x; q0 += x * x;
    s1 += y; q1 += y * y;
  }
  int c0 = 2 * t;
  sumP[(size_t)c0 * 256 + b]       = s0;
  sumP[(size_t)(c0 + 1) * 256 + b] = s1;
  sqP [(size_t)c0 * 256 + b]       = q0;
  sqP [(size_t)(c0 + 1) * 256 + b] = q1;
}

// ---------------- BN stats stage 2: per-channel a, b in f64 ------------------
__global__ __launch_bounds__(512) void k_stats2(const double* __restrict__ sumP,
                                                const double* __restrict__ sqP,
                                                const float* __restrict__ gamma,
                                                const float* __restrict__ beta,
                                                double* __restrict__ sA,
                                                double* __restrict__ sB) {
  int c = threadIdx.x;      // 512 channels, 1 block (deterministic)
  double s = 0, q = 0;
  for (int b = 0; b < 256; ++b) {
    s += sumP[(size_t)c * 256 + b];
    q += sqP [(size_t)c * 256 + b];
  }
  const double invN = 1.0 / 32768.0;
  double mean = s * invN;
  double var  = q * invN - mean * mean;
  double rstd = rsqrt(var + 1e-5);
  double a = (double)gamma[c] * rstd;
  sA[c] = a;
  sB[c] = (double)beta[c] - mean * a;
}

// ---------------- final: out = f32(f64(y)*a + b + x) ------------------------
__global__ __launch_bounds__(256) void k_final(float* __restrict__ Y,
                                               const float* __restrict__ X,
                                               const double* __restrict__ sA,
                                               const double* __restrict__ sB) {
  size_t i = (size_t)blockIdx.x * 256 + threadIdx.x;  // float4 index
  int c0 = (int)((i * 4) & (CH - 1));
  float4 y = ((const float4*)Y)[i];
  float4 x = ((const float4*)X)[i];
  float4 o;
  o.x = (float)((double)y.x * sA[c0 + 0] + sB[c0 + 0] + (double)x.x);
  o.y = (float)((double)y.y * sA[c0 + 1] + sB[c0 + 1] + (double)x.y);
  o.z = (float)((double)y.z * sA[c0 + 2] + sB[c0 + 2] + (double)x.z);
  o.w = (float)((double)y.w * sA[c0 + 3] + sB[c0 + 3] + (double)x.w);
  ((float4*)Y)[i] = o;
}

// ---------------- launch ----------------------------------------------------
extern "C" void kernel_launch(void* const* d_in, const int* in_sizes, int n_in,
                              void* d_out, int out_size, void* d_ws, size_t ws_size,
                              hipStream_t stream) {
  (void)in_sizes; (void)n_in; (void)out_size; (void)ws_size;

  const float* x   = (const float*)d_in[0];
  const float* w0  = (const float*)d_in[1];
  const float* W0  = (const float*)d_in[2];
  // d_in[3] = b0: absorbed by BN
  const float* g0  = (const float*)d_in[4];
  const float* be0 = (const float*)d_in[5];
  const float* w1  = (const float*)d_in[6];
  const float* W1  = (const float*)d_in[7];
  // d_in[8] = b1: absorbed by BN
  const float* g1  = (const float*)d_in[9];
  const float* be1 = (const float*)d_in[10];
  float* Y = (float*)d_out;   // y1, then y2, then final output

  char* ws = (char*)d_ws;
  double* Wt0  = (double*)(ws + 0x0000000);  // 2 MB
  double* Wt1  = (double*)(ws + 0x0200000);  // 2 MB
  bf16*   spk  = (bf16*)  (ws + 0x0400000);  // 33.5 MB
  double* sumP = (double*)(ws + 0x2600000);  // 1 MB
  double* sqP  = (double*)(ws + 0x2700000);  // 1 MB
  double* sA   = (double*)(ws + 0x2800000);  // 4 KB
  double* sB   = (double*)(ws + 0x2802000);  // 4 KB

  k_convw<<<1024, 256, 0, stream>>>(W0, Wt0);
  k_convw<<<1024, 256, 0, stream>>>(W1, Wt1);

  // block 1
  k_lif1 <<<BC / 256, 256, 0, stream>>>(x, w0, spk);
  k_gemm <<<(MROWS / 64) * (CH / 128), 256, 0, stream>>>(spk, Wt0, Y);
  k_stats1<<<256, 256, 0, stream>>>(Y, sumP, sqP);
  k_stats2<<<1, 512, 0, stream>>>(sumP, sqP, g0, be0, sA, sB);

  // block 2 (BN affine of block 1 fused into LIF input, f64->f32 once)
  k_lif2 <<<BC / 256, 256, 0, stream>>>(Y, sA, sB, w1, spk);
  k_gemm <<<(MROWS / 64) * (CH / 128), 256, 0, stream>>>(spk, Wt1, Y);
  k_stats1<<<256, 256, 0, stream>>>(Y, sumP, sqP);
  k_stats2<<<1, 512, 0, stream>>>(sumP, sqP, g1, be1, sA, sB);

  // out = BN(y2) + x
  k_final<<<(MROWS * CH) / (4 * 256), 256, 0, stream>>>(Y, x, sA, sB);
}

// Round 3
// 372.008 us; speedup vs baseline: 2.4808x; 2.4808x over previous
//
#include <hip/hip_runtime.h>

// LTLIF(tau=2, decay_input=False, hard reset) -> Linear -> BN, x2 blocks, +skip.
// T=128, B=256, C=512. GEMMs: M=T*B=32768, K=N=512.
//
// Round 3: spikes are BINARY, so y = S@W^T is a subset-sum of W rows. W is
// quantized to 32-bit fixed point (scale 2^32, |W|<=~0.22 so exact-safe) and
// split into 4 signed i8 limbs. Each limb GEMM runs on v_mfma_i32_16x16x32_i8
// with EXACT i32 accumulation (|sum| <= 512*128 = 2^16, no overflow); limbs
// combine exactly in f64. Total deviation from the round-2 f64 pipeline is
// only W-quantization: <= 512*2^-33 ~ 6e-8 worst case -> flip-equivalent.
// The K=32 i8 MFMA fragment math is identical to the HW-verified bf16
// 16x16x32 layout (8 elems/lane, k=(lane>>4)*8+j; C/D dtype-independent).
// LDS reads use a 16B-granular XOR swizzle, applied BOTH sides (pre-swizzled
// global source for global_load_lds + swizzled ds_read addr).

typedef long   i64;
typedef int    i32x4 __attribute__((ext_vector_type(4)));

#define T_STEPS 128
#define BATCH   256
#define CH      512
#define BC      (BATCH * CH)        // 131072
#define MROWS   (T_STEPS * BATCH)   // 32768

// ---------------- async global->LDS (16B per lane, wave-uniform LDS base) ----
__device__ __forceinline__ void llds16(const void* g, void* l) {
  __builtin_amdgcn_global_load_lds(
      (const __attribute__((address_space(1))) void*)g,
      (__attribute__((address_space(3))) void*)l, 16, 0, 0);
}

// ---------------- W f32 -> 4 signed i8 limb planes (fixed point, scale 2^32) -
__global__ __launch_bounds__(256) void k_convw(const float* __restrict__ W,
                                               signed char* __restrict__ WL) {
  int i = blockIdx.x * 256 + threadIdx.x;   // 262144
  double z = (double)W[i] * 4294967296.0;
  z = fmin(fmax(z, -2147483647.0), 2147483647.0);  // safety clamp (never hit)
  int q = (int)llrint(z);
  int r = q;
  signed char l0 = (signed char)r; r = (r - l0) >> 8;
  signed char l1 = (signed char)r; r = (r - l1) >> 8;
  signed char l2 = (signed char)r; r = (r - l2) >> 8;
  signed char l3 = (signed char)r;
  WL[i]          = l0;
  WL[i + 262144] = l1;
  WL[i + 524288] = l2;
  WL[i + 786432] = l3;
}

// ---------------- LIF scan, block 1: x -> spikes (f32, bit-exact) -----------
__global__ __launch_bounds__(256) void k_lif1(const float* __restrict__ X,
                                              const float* __restrict__ wp,
                                              signed char* __restrict__ S) {
  int i4 = blockIdx.x * 256 + threadIdx.x;     // group of 4 channels
  float inv_tau = 1.0f / (1.0f + expf(-wp[0]));
  float om = 1.0f - inv_tau;
  float v0 = 0.f, v1 = 0.f, v2 = 0.f, v3 = 0.f;
  for (int t = 0; t < T_STEPS; ++t) {
    float4 x = ((const float4*)X)[(size_t)t * (BC / 4) + i4];
    char4 s;
    v0 = v0 * om + x.x; s.x = (v0 >= 1.f); v0 = s.x ? 0.f : v0;
    v1 = v1 * om + x.y; s.y = (v1 >= 1.f); v1 = s.y ? 0.f : v1;
    v2 = v2 * om + x.z; s.z = (v2 >= 1.f); v2 = s.z ? 0.f : v2;
    v3 = v3 * om + x.w; s.w = (v3 >= 1.f); v3 = s.w ? 0.f : v3;
    ((char4*)S)[(size_t)t * (BC / 4) + i4] = s;
  }
}

// ---------------- LIF scan, block 2: h = f32(f64(y)*a+b) -> spikes ----------
__global__ __launch_bounds__(256) void k_lif2(const float* __restrict__ Y,
                                              const double* __restrict__ sA,
                                              const double* __restrict__ sB,
                                              const float* __restrict__ wp,
                                              signed char* __restrict__ S) {
  int i4 = blockIdx.x * 256 + threadIdx.x;
  int c0 = (i4 * 4) & (CH - 1);
  double a0 = sA[c0], a1 = sA[c0 + 1], a2 = sA[c0 + 2], a3 = sA[c0 + 3];
  double b0 = sB[c0], b1 = sB[c0 + 1], b2 = sB[c0 + 2], b3 = sB[c0 + 3];
  float inv_tau = 1.0f / (1.0f + expf(-wp[0]));
  float om = 1.0f - inv_tau;
  float v0 = 0.f, v1 = 0.f, v2 = 0.f, v3 = 0.f;
  for (int t = 0; t < T_STEPS; ++t) {
    float4 y = ((const float4*)Y)[(size_t)t * (BC / 4) + i4];
    char4 s;
    float h0 = (float)((double)y.x * a0 + b0);
    float h1 = (float)((double)y.y * a1 + b1);
    float h2 = (float)((double)y.z * a2 + b2);
    float h3 = (float)((double)y.w * a3 + b3);
    v0 = v0 * om + h0; s.x = (v0 >= 1.f); v0 = s.x ? 0.f : v0;
    v1 = v1 * om + h1; s.y = (v1 >= 1.f); v1 = s.y ? 0.f : v1;
    v2 = v2 * om + h2; s.z = (v2 >= 1.f); v2 = s.z ? 0.f : v2;
    v3 = v3 * om + h3; s.w = (v3 >= 1.f); v3 = s.w ? 0.f : v3;
    ((char4*)S)[(size_t)t * (BC / 4) + i4] = s;
  }
}

// ---------------- i8 limb GEMM: Y[m][d] = (sum_j 256^j * S@L_j^T) * 2^-32 ----
// Block tile 64(M) x 128(N), BK=64, 4 waves (2x2), wave tile 32x64 = 2x4 frags.
// 16B-granular XOR swizzle: LDS chunk c16 holds global chunk c16^((row>>1)&3);
// read slot s' = s ^ (((row>>1)&3)<<1). Residual 2-way conflict is free.
__global__ __launch_bounds__(256) void k_gemm(const signed char* __restrict__ S,
                                              const signed char* __restrict__ WL,
                                              float* __restrict__ Y) {
  __shared__ __align__(16) signed char Ab[64 * 64];       // 4 KB
  __shared__ __align__(16) signed char Bp[4][128 * 64];   // 32 KB

  const int tid  = threadIdx.x;
  const int wid  = tid >> 6;
  const int lane = tid & 63;
  const int bid  = blockIdx.x;
  const int bm = bid & 511, bn = bid >> 9;   // consecutive bids share bn
  const int m0 = bm * 64, n0 = bn * 128;
  const int wm = wid >> 1, wn = wid & 1;

  i32x4 acc[2][4][4] = {};   // [m][n][limb]

  for (int kt = 0; kt < 512; kt += 64) {
    // stage A: 256 x 16B chunks (1/thread); cid=tid -> row=tid>>2, c16=tid&3
    {
      int row = tid >> 2, c16l = tid & 3;
      int c16g = c16l ^ ((row >> 1) & 3);
      llds16(S + (size_t)(m0 + row) * 512 + kt + c16g * 16,
             (char*)Ab + wid * 1024);
    }
    // stage B: 4 limb planes x 512 chunks (2/thread each)
    #pragma unroll
    for (int j = 0; j < 4; ++j)
      #pragma unroll
      for (int p = 0; p < 2; ++p) {
        int cid = p * 256 + tid;
        int row = cid >> 2, c16l = cid & 3;
        int c16g = c16l ^ ((row >> 1) & 3);
        llds16(WL + (size_t)j * 262144 + (size_t)(n0 + row) * 512 + kt + c16g * 16,
               (char*)Bp[j] + (p * 4 + wid) * 1024);
      }
    __syncthreads();

    #pragma unroll
    for (int ks = 0; ks < 2; ++ks) {
      i64 a[2], b[4][4];
      #pragma unroll
      for (int m = 0; m < 2; ++m) {
        int r = wm * 32 + m * 16 + (lane & 15);
        int s = (ks * 4 + (lane >> 4)) ^ (((r >> 1) & 3) << 1);
        a[m] = *(const i64*)(Ab + r * 64 + s * 8);
      }
      #pragma unroll
      for (int n = 0; n < 4; ++n) {
        int r = wn * 64 + n * 16 + (lane & 15);
        int s = (ks * 4 + (lane >> 4)) ^ (((r >> 1) & 3) << 1);
        #pragma unroll
        for (int j = 0; j < 4; ++j)
          b[n][j] = *(const i64*)(Bp[j] + r * 64 + s * 8);
      }
      #pragma unroll
      for (int m = 0; m < 2; ++m)
        #pragma unroll
        for (int n = 0; n < 4; ++n)
          #pragma unroll
          for (int j = 0; j < 4; ++j)
            acc[m][n][j] = __builtin_amdgcn_mfma_i32_16x16x32_i8(
                a[m], b[n][j], acc[m][n][j], 0, 0, 0);
    }
    __syncthreads();
  }

  // C/D layout (dtype-independent): col = lane&15, row = (lane>>4)*4 + q
  const int r0 = m0 + wm * 32 + (lane >> 4) * 4;
  const int c0 = n0 + wn * 64 + (lane & 15);
  #pragma unroll
  for (int m = 0; m < 2; ++m)
    #pragma unroll
    for (int n = 0; n < 4; ++n)
      #pragma unroll
      for (int q = 0; q < 4; ++q) {
        double y = (((double)acc[m][n][3][q] * 256.0 + (double)acc[m][n][2][q]) * 256.0
                    + (double)acc[m][n][1][q]) * 256.0 + (double)acc[m][n][0][q];
        Y[(size_t)(r0 + m * 16 + q) * 512 + (c0 + n * 16)] = (float)(y * 0x1p-32);
      }
}

// ---------------- BN stats stage 1: f64 partials, layout [p=256][ch=512] ----
__global__ __launch_bounds__(256) void k_stats1(const float* __restrict__ Y,
                                                double* __restrict__ sumP,
                                                double* __restrict__ sqP) {
  int b = blockIdx.x;       // 256 blocks x 128 rows
  int t = threadIdx.x;      // channels 2t, 2t+1
  const float2* base = (const float2*)(Y + (size_t)b * 128 * CH) + t;
  double s0 = 0, q0 = 0, s1 = 0, q1 = 0;
  #pragma unroll 4
  for (int r = 0; r < 128; ++r) {
    float2 v = base[(size_t)r * 256];
    double x = v.x, y = v.y;
    s0 += x; q0 += x * x;
    s1 += y; q1 += y * y;
  }
  int c0 = 2 * t;
  sumP[(size_t)b * CH + c0]     = s0;
  sumP[(size_t)b * CH + c0 + 1] = s1;
  sqP [(size_t)b * CH + c0]     = q0;
  sqP [(size_t)b * CH + c0 + 1] = q1;
}

// ---------------- BN stats stage 2: per-channel a, b (2 blocks, coalesced) ---
__global__ __launch_bounds__(256) void k_stats2(const double* __restrict__ sumP,
                                                const double* __restrict__ sqP,
                                                const float* __restrict__ gamma,
                                                const float* __restrict__ beta,
                                                double* __restrict__ sA,
                                                double* __restrict__ sB) {
  int c = blockIdx.x * 256 + threadIdx.x;   // 512 channels over 2 blocks
  double s = 0, q = 0;
  for (int p = 0; p < 256; ++p) {           // fixed order: deterministic
    s += sumP[(size_t)p * CH + c];
    q += sqP [(size_t)p * CH + c];
  }
  const double invN = 1.0 / 32768.0;
  double mean = s * invN;
  double var  = q * invN - mean * mean;
  double rstd = rsqrt(var + 1e-5);
  double a = (double)gamma[c] * rstd;
  sA[c] = a;
  sB[c] = (double)beta[c] - mean * a;
}

// ---------------- final: out = f32(f64(y)*a + b + x) ------------------------
__global__ __launch_bounds__(256) void k_final(float* __restrict__ Y,
                                               const float* __restrict__ X,
                                               const double* __restrict__ sA,
                                               const double* __restrict__ sB) {
  size_t i = (size_t)blockIdx.x * 256 + threadIdx.x;  // float4 index
  int c0 = (int)((i * 4) & (CH - 1));
  float4 y = ((const float4*)Y)[i];
  float4 x = ((const float4*)X)[i];
  float4 o;
  o.x = (float)((double)y.x * sA[c0 + 0] + sB[c0 + 0] + (double)x.x);
  o.y = (float)((double)y.y * sA[c0 + 1] + sB[c0 + 1] + (double)x.y);
  o.z = (float)((double)y.z * sA[c0 + 2] + sB[c0 + 2] + (double)x.z);
  o.w = (float)((double)y.w * sA[c0 + 3] + sB[c0 + 3] + (double)x.w);
  ((float4*)Y)[i] = o;
}

// ---------------- launch ----------------------------------------------------
extern "C" void kernel_launch(void* const* d_in, const int* in_sizes, int n_in,
                              void* d_out, int out_size, void* d_ws, size_t ws_size,
                              hipStream_t stream) {
  (void)in_sizes; (void)n_in; (void)out_size; (void)ws_size;

  const float* x   = (const float*)d_in[0];
  const float* w0  = (const float*)d_in[1];
  const float* W0  = (const float*)d_in[2];
  // d_in[3] = b0: absorbed by BN
  const float* g0  = (const float*)d_in[4];
  const float* be0 = (const float*)d_in[5];
  const float* w1  = (const float*)d_in[6];
  const float* W1  = (const float*)d_in[7];
  // d_in[8] = b1: absorbed by BN
  const float* g1  = (const float*)d_in[9];
  const float* be1 = (const float*)d_in[10];
  float* Y = (float*)d_out;   // y1, then y2, then final output

  char* ws = (char*)d_ws;
  signed char* WL0  = (signed char*)(ws + 0x0000000);  // 1 MB (4 planes)
  signed char* WL1  = (signed char*)(ws + 0x0100000);  // 1 MB
  signed char* spk  = (signed char*)(ws + 0x0200000);  // 16.78 MB
  double*      sumP = (double*)(ws + 0x1200000);       // 1 MB
  double*      sqP  = (double*)(ws + 0x1300000);       // 1 MB
  double*      sA   = (double*)(ws + 0x1400000);       // 4 KB
  double*      sB   = (double*)(ws + 0x1402000);       // 4 KB

  k_convw<<<1024, 256, 0, stream>>>(W0, WL0);
  k_convw<<<1024, 256, 0, stream>>>(W1, WL1);

  // block 1
  k_lif1 <<<BC / 4 / 256, 256, 0, stream>>>(x, w0, spk);
  k_gemm <<<(MROWS / 64) * (CH / 128), 256, 0, stream>>>(spk, WL0, Y);
  k_stats1<<<256, 256, 0, stream>>>(Y, sumP, sqP);
  k_stats2<<<2, 256, 0, stream>>>(sumP, sqP, g0, be0, sA, sB);

  // block 2 (BN affine of block 1 fused into LIF input, f64->f32 once)
  k_lif2 <<<BC / 4 / 256, 256, 0, stream>>>(Y, sA, sB, w1, spk);
  k_gemm <<<(MROWS / 64) * (CH / 128), 256, 0, stream>>>(spk, WL1, Y);
  k_stats1<<<256, 256, 0, stream>>>(Y, sumP, sqP);
  k_stats2<<<2, 256, 0, stream>>>(sumP, sqP, g1, be1, sA, sB);

  // out = BN(y2) + x
  k_final<<<(MROWS * CH) / (4 * 256), 256, 0, stream>>>(Y, x, sA, sB);
}

// Round 4
// 252.449 us; speedup vs baseline: 3.6557x; 1.4736x over previous
//
#include <hip/hip_runtime.h>

// LTLIF(tau=2, decay_input=False, hard reset) -> Linear -> BN, x2 blocks, +skip.
// T=128, B=256, C=512. GEMMs: M=T*B=32768, K=N=512.
//
// Round 4: exact i8-limb GEMM (4 limbs, scale 2^32, i32 accum exact, f64
// combine) upgraded to v_mfma_i32_16x16x64_i8 (2x MACs/inst at the same
// ~5cy 16x16 issue rate). Tile 128M x 64N, BK=64, 4 waves (2x2), LDS
// double-buffered (48 KB) with stage-next-before-compute + single barrier
// per K-step. BN partial stats fused into the GEMM epilogue (shfl reduce +
// LDS cross-wave, fixed-order f64, no atomics). Any k-permutation inside
// the 16B fragment cancels between A and B; C/D layout is dtype-independent.

typedef int i32x4 __attribute__((ext_vector_type(4)));

#define T_STEPS 128
#define BATCH   256
#define CH      512
#define BC      (BATCH * CH)        // 131072
#define MROWS   (T_STEPS * BATCH)   // 32768

// ---------------- async global->LDS (16B per lane, wave-uniform LDS base) ----
__device__ __forceinline__ void llds16(const void* g, void* l) {
  __builtin_amdgcn_global_load_lds(
      (const __attribute__((address_space(1))) void*)g,
      (__attribute__((address_space(3))) void*)l, 16, 0, 0);
}

// ---------------- W f32 -> 4 signed i8 limb planes (fixed point, scale 2^32) -
__global__ __launch_bounds__(256) void k_convw(const float* __restrict__ W,
                                               signed char* __restrict__ WL) {
  int i = blockIdx.x * 256 + threadIdx.x;   // 262144
  double z = (double)W[i] * 4294967296.0;
  z = fmin(fmax(z, -2147483647.0), 2147483647.0);  // safety clamp (never hit)
  int q = (int)llrint(z);
  int r = q;
  signed char l0 = (signed char)r; r = (r - l0) >> 8;
  signed char l1 = (signed char)r; r = (r - l1) >> 8;
  signed char l2 = (signed char)r; r = (r - l2) >> 8;
  signed char l3 = (signed char)r;
  WL[i]          = l0;
  WL[i + 262144] = l1;
  WL[i + 524288] = l2;
  WL[i + 786432] = l3;
}

// ---------------- LIF scan, block 1: x -> spikes (f32, bit-exact) -----------
__global__ __launch_bounds__(256) void k_lif1(const float* __restrict__ X,
                                              const float* __restrict__ wp,
                                              signed char* __restrict__ S) {
  int i4 = blockIdx.x * 256 + threadIdx.x;     // group of 4 channels
  float inv_tau = 1.0f / (1.0f + expf(-wp[0]));
  float om = 1.0f - inv_tau;
  float v0 = 0.f, v1 = 0.f, v2 = 0.f, v3 = 0.f;
  for (int t = 0; t < T_STEPS; ++t) {
    float4 x = ((const float4*)X)[(size_t)t * (BC / 4) + i4];
    char4 s;
    v0 = v0 * om + x.x; s.x = (v0 >= 1.f); v0 = s.x ? 0.f : v0;
    v1 = v1 * om + x.y; s.y = (v1 >= 1.f); v1 = s.y ? 0.f : v1;
    v2 = v2 * om + x.z; s.z = (v2 >= 1.f); v2 = s.z ? 0.f : v2;
    v3 = v3 * om + x.w; s.w = (v3 >= 1.f); v3 = s.w ? 0.f : v3;
    ((char4*)S)[(size_t)t * (BC / 4) + i4] = s;
  }
}

// ---------------- LIF scan, block 2: h = f32(f64(y)*a+b) -> spikes ----------
__global__ __launch_bounds__(256) void k_lif2(const float* __restrict__ Y,
                                              const double* __restrict__ sA,
                                              const double* __restrict__ sB,
                                              const float* __restrict__ wp,
                                              signed char* __restrict__ S) {
  int i4 = blockIdx.x * 256 + threadIdx.x;
  int c0 = (i4 * 4) & (CH - 1);
  double a0 = sA[c0], a1 = sA[c0 + 1], a2 = sA[c0 + 2], a3 = sA[c0 + 3];
  double b0 = sB[c0], b1 = sB[c0 + 1], b2 = sB[c0 + 2], b3 = sB[c0 + 3];
  float inv_tau = 1.0f / (1.0f + expf(-wp[0]));
  float om = 1.0f - inv_tau;
  float v0 = 0.f, v1 = 0.f, v2 = 0.f, v3 = 0.f;
  for (int t = 0; t < T_STEPS; ++t) {
    float4 y = ((const float4*)Y)[(size_t)t * (BC / 4) + i4];
    char4 s;
    float h0 = (float)((double)y.x * a0 + b0);
    float h1 = (float)((double)y.y * a1 + b1);
    float h2 = (float)((double)y.z * a2 + b2);
    float h3 = (float)((double)y.w * a3 + b3);
    v0 = v0 * om + h0; s.x = (v0 >= 1.f); v0 = s.x ? 0.f : v0;
    v1 = v1 * om + h1; s.y = (v1 >= 1.f); v1 = s.y ? 0.f : v1;
    v2 = v2 * om + h2; s.z = (v2 >= 1.f); v2 = s.z ? 0.f : v2;
    v3 = v3 * om + h3; s.w = (v3 >= 1.f); v3 = s.w ? 0.f : v3;
    ((char4*)S)[(size_t)t * (BC / 4) + i4] = s;
  }
}

// ---------------- i8 limb GEMM + fused BN partial stats ----------------------
// Tile 128(M) x 64(N), BK=64, dbuf LDS, 4 waves (2Mx2N); wave tile 64x32.
// K=64 MFMA: lane fragment = 16 i8 at k-granule (lane>>4); 16B XOR swizzle
// (granule ^ ((row>>1)&3)) applied on BOTH sides (pre-swizzled global src,
// swizzled ds_read addr). Epilogue: limb combine (f64 exact), Y write, and
// per-(bm, channel) f64 sum/sumsq partials (shfl + LDS, fixed order).
__global__ __launch_bounds__(256) void k_gemm(const signed char* __restrict__ S,
                                              const signed char* __restrict__ WL,
                                              float* __restrict__ Y,
                                              double* __restrict__ sumP,
                                              double* __restrict__ sqP) {
  __shared__ __align__(16) signed char Ab[2][128 * 64];      // 8 KB x2
  __shared__ __align__(16) signed char Bb[2][4][64 * 64];    // 16 KB x2

  const int tid  = threadIdx.x;
  const int wid  = tid >> 6;
  const int lane = tid & 63;
  const int bid  = blockIdx.x;
  const int bm = bid & 255, bn = bid >> 8;   // bm fastest: W panel L2-hot
  const int m0 = bm * 128, n0 = bn * 64;
  const int wm = wid >> 1, wn = wid & 1;

  i32x4 acc[4][2][4] = {};   // [m-frag][n-frag][limb]

  // stage one BK=64 tile into buffer `buf` (pre-swizzled source granules)
  auto STAGE = [&](int buf, int kt) {
    #pragma unroll
    for (int p = 0; p < 2; ++p) {                 // A: 128 rows x 4 granules
      int cid = p * 256 + tid, row = cid >> 2, gl = cid & 3;
      int gg = gl ^ ((row >> 1) & 3);
      llds16(S + (size_t)(m0 + row) * 512 + kt + gg * 16,
             (char*)Ab[buf] + p * 4096 + wid * 1024);
    }
    #pragma unroll
    for (int j = 0; j < 4; ++j) {                 // B: 4 limbs x 64 rows x 4
      int row = tid >> 2, gl = tid & 3;
      int gg = gl ^ ((row >> 1) & 3);
      llds16(WL + (size_t)j * 262144 + (size_t)(n0 + row) * 512 + kt + gg * 16,
             (char*)Bb[buf][j] + wid * 1024);
    }
  };

  STAGE(0, 0);
  __syncthreads();
  int cur = 0;
  for (int kt64 = 0; kt64 < 8; ++kt64) {
    if (kt64 < 7) STAGE(cur ^ 1, (kt64 + 1) * 64);   // prefetch next tile

    i32x4 a[4];
    #pragma unroll
    for (int m = 0; m < 4; ++m) {
      int r = wm * 64 + m * 16 + (lane & 15);
      int g = (lane >> 4) ^ ((r >> 1) & 3);
      a[m] = *(const i32x4*)(Ab[cur] + r * 64 + g * 16);
    }
    #pragma unroll
    for (int j = 0; j < 4; ++j) {
      i32x4 b[2];
      #pragma unroll
      for (int n = 0; n < 2; ++n) {
        int r = wn * 32 + n * 16 + (lane & 15);
        int g = (lane >> 4) ^ ((r >> 1) & 3);
        b[n] = *(const i32x4*)(Bb[cur][j] + r * 64 + g * 16);
      }
      #pragma unroll
      for (int m = 0; m < 4; ++m)
        #pragma unroll
        for (int n = 0; n < 2; ++n)
          acc[m][n][j] = __builtin_amdgcn_mfma_i32_16x16x64_i8(
              a[m], b[n], acc[m][n][j], 0, 0, 0);
    }
    __syncthreads();   // drains this iter's prefetch (vmcnt0) + read fence
    cur ^= 1;
  }

  // ---- epilogue: limb combine, Y write, fused BN partials -------------------
  // C/D: col = lane&15 (+16n +32wn), row = (lane>>4)*4 + q (+16m +64wm)
  const int r0 = m0 + wm * 64 + (lane >> 4) * 4;
  const int cl = wn * 32 + (lane & 15);      // block-local col of n=0 frag
  double s0 = 0, q0 = 0, s1 = 0, q1 = 0;
  #pragma unroll
  for (int m = 0; m < 4; ++m)
    #pragma unroll
    for (int n = 0; n < 2; ++n)
      #pragma unroll
      for (int q = 0; q < 4; ++q) {
        double yv = (((double)acc[m][n][3][q] * 256.0 + (double)acc[m][n][2][q]) * 256.0
                     + (double)acc[m][n][1][q]) * 256.0 + (double)acc[m][n][0][q];
        float yf = (float)(yv * 0x1p-32);
        Y[(size_t)(r0 + m * 16 + q) * 512 + n0 + cl + n * 16] = yf;
        double yd = (double)yf;
        if (n == 0) { s0 += yd; q0 += yd * yd; }
        else        { s1 += yd; q1 += yd * yd; }
      }
  // reduce across the 4 lane-groups (rows of this wave): lanes l, l+16, l+32, l+48
  s0 += __shfl_xor(s0, 16); s0 += __shfl_xor(s0, 32);
  q0 += __shfl_xor(q0, 16); q0 += __shfl_xor(q0, 32);
  s1 += __shfl_xor(s1, 16); s1 += __shfl_xor(s1, 32);
  q1 += __shfl_xor(q1, 16); q1 += __shfl_xor(q1, 32);

  double* shS = (double*)Ab[0];        // reuse LDS (post-barrier, dead)
  double* shQ = shS + 128;
  if (lane < 16) {
    shS[wm * 64 + cl]      = s0;  shQ[wm * 64 + cl]      = q0;
    shS[wm * 64 + cl + 16] = s1;  shQ[wm * 64 + cl + 16] = q1;
  }
  __syncthreads();
  if (tid < 64) {   // cross-wave (wm) add; col = tid; fixed order
    sumP[(size_t)bm * 512 + n0 + tid] = shS[tid] + shS[64 + tid];
    sqP [(size_t)bm * 512 + n0 + tid] = shQ[tid] + shQ[64 + tid];
  }
}

// ---------------- BN stats stage 2: per-channel a, b (coalesced) -------------
__global__ __launch_bounds__(256) void k_stats2(const double* __restrict__ sumP,
                                                const double* __restrict__ sqP,
                                                const float* __restrict__ gamma,
                                                const float* __restrict__ beta,
                                                double* __restrict__ sA,
                                                double* __restrict__ sB) {
  int c = blockIdx.x * 256 + threadIdx.x;   // 512 channels over 2 blocks
  double s = 0, q = 0;
  for (int p = 0; p < 256; ++p) {           // fixed order: deterministic
    s += sumP[(size_t)p * CH + c];
    q += sqP [(size_t)p * CH + c];
  }
  const double invN = 1.0 / 32768.0;
  double mean = s * invN;
  double var  = q * invN - mean * mean;
  double rstd = rsqrt(var + 1e-5);
  double a = (double)gamma[c] * rstd;
  sA[c] = a;
  sB[c] = (double)beta[c] - mean * a;
}

// ---------------- final: out = f32(f64(y)*a + b + x) ------------------------
__global__ __launch_bounds__(256) void k_final(float* __restrict__ Y,
                                               const float* __restrict__ X,
                                               const double* __restrict__ sA,
                                               const double* __restrict__ sB) {
  size_t i = (size_t)blockIdx.x * 256 + threadIdx.x;  // float4 index
  int c0 = (int)((i * 4) & (CH - 1));
  float4 y = ((const float4*)Y)[i];
  float4 x = ((const float4*)X)[i];
  float4 o;
  o.x = (float)((double)y.x * sA[c0 + 0] + sB[c0 + 0] + (double)x.x);
  o.y = (float)((double)y.y * sA[c0 + 1] + sB[c0 + 1] + (double)x.y);
  o.z = (float)((double)y.z * sA[c0 + 2] + sB[c0 + 2] + (double)x.z);
  o.w = (float)((double)y.w * sA[c0 + 3] + sB[c0 + 3] + (double)x.w);
  ((float4*)Y)[i] = o;
}

// ---------------- launch ----------------------------------------------------
extern "C" void kernel_launch(void* const* d_in, const int* in_sizes, int n_in,
                              void* d_out, int out_size, void* d_ws, size_t ws_size,
                              hipStream_t stream) {
  (void)in_sizes; (void)n_in; (void)out_size; (void)ws_size;

  const float* x   = (const float*)d_in[0];
  const float* w0  = (const float*)d_in[1];
  const float* W0  = (const float*)d_in[2];
  // d_in[3] = b0: absorbed by BN
  const float* g0  = (const float*)d_in[4];
  const float* be0 = (const float*)d_in[5];
  const float* w1  = (const float*)d_in[6];
  const float* W1  = (const float*)d_in[7];
  // d_in[8] = b1: absorbed by BN
  const float* g1  = (const float*)d_in[9];
  const float* be1 = (const float*)d_in[10];
  float* Y = (float*)d_out;   // y1, then y2, then final output

  char* ws = (char*)d_ws;
  signed char* WL0  = (signed char*)(ws + 0x0000000);  // 1 MB (4 planes)
  signed char* WL1  = (signed char*)(ws + 0x0100000);  // 1 MB
  signed char* spk  = (signed char*)(ws + 0x0200000);  // 16.78 MB
  double*      sumP = (double*)(ws + 0x1200000);       // 1 MB
  double*      sqP  = (double*)(ws + 0x1300000);       // 1 MB
  double*      sA   = (double*)(ws + 0x1400000);       // 4 KB
  double*      sB   = (double*)(ws + 0x1402000);       // 4 KB

  k_convw<<<1024, 256, 0, stream>>>(W0, WL0);
  k_convw<<<1024, 256, 0, stream>>>(W1, WL1);

  // block 1
  k_lif1 <<<BC / 4 / 256, 256, 0, stream>>>(x, w0, spk);
  k_gemm <<<(MROWS / 128) * (CH / 64), 256, 0, stream>>>(spk, WL0, Y, sumP, sqP);
  k_stats2<<<2, 256, 0, stream>>>(sumP, sqP, g0, be0, sA, sB);

  // block 2 (BN affine of block 1 fused into LIF input, f64->f32 once)
  k_lif2 <<<BC / 4 / 256, 256, 0, stream>>>(Y, sA, sB, w1, spk);
  k_gemm <<<(MROWS / 128) * (CH / 64), 256, 0, stream>>>(spk, WL1, Y, sumP, sqP);
  k_stats2<<<2, 256, 0, stream>>>(sumP, sqP, g1, be1, sA, sB);

  // out = BN(y2) + x
  k_final<<<(MROWS * CH) / (4 * 256), 256, 0, stream>>>(Y, x, sA, sB);
}